// Round 6
// baseline (266.386 us; speedup 1.0000x reference)
//
#include <hip/hip_runtime.h>
#include <hip/hip_bf16.h>
#include <stdint.h>

#define TOKENS 4096
#define IN_F   4096
#define OUT_F  4096
#define NNZ    512

using floatx16 = __attribute__((ext_vector_type(16))) float;
using bf16x8   = __attribute__((ext_vector_type(8))) __bf16;

__device__ __forceinline__ unsigned short f2bf(float f) {
    unsigned int u = __float_as_uint(f);
    u += 0x7FFFu + ((u >> 16) & 1u);   // round-to-nearest-even
    return (unsigned short)(u >> 16);
}

// ---------------------------------------------------------------------------
// Prep (R4 structure, unchanged — residual shown invariant to prep structure):
//  blocks [0, 1024)    : W path. 4 waves/block, one row per wave, no barriers.
//  blocks [1024, 3072) : X path. fp32 -> bf16, 4 iters x 8 elems per thread.
// ---------------------------------------------------------------------------
__global__ __launch_bounds__(256) void prep_fused(
        const float* __restrict__ x,
        const float* __restrict__ w,
        const int*   __restrict__ mask,
        unsigned short* __restrict__ Xb,
        unsigned short* __restrict__ Wb) {
    __shared__ unsigned short rows[4][IN_F];   // 32 KB
    const int b = blockIdx.x;
    const int t = threadIdx.x;

    if (b < 1024) {
        const int wave = t >> 6;
        const int lane = t & 63;
        const int rrow = b * 4 + wave;
        unsigned short* row = rows[wave];
        uint4* rv = (uint4*)row;
        const uint4 z = make_uint4(0u, 0u, 0u, 0u);
#pragma unroll
        for (int j = 0; j < 8; ++j) rv[lane + 64 * j] = z;   // 512 uint4 = full row

        const int base = rrow * NNZ;
        const int4*   m4 = (const int4*)(mask + base);
        const float4* w4 = (const float4*)(w + base);
        const int4   ma = m4[2 * lane], mb2 = m4[2 * lane + 1];
        const float4 wa = w4[2 * lane], wb2 = w4[2 * lane + 1];
        const int   mk[8] = {ma.x, ma.y, ma.z, ma.w, mb2.x, mb2.y, mb2.z, mb2.w};
        const float wk[8] = {wa.x, wa.y, wa.z, wa.w, wb2.x, wb2.y, wb2.z, wb2.w};

        // run-leader scan: one owner lane per run of equal sorted indices.
        int   cur = (lane == 0) ? -1 : mask[base + 8 * lane - 1];
        float s   = 0.0f;
        bool  own = false;
#pragma unroll
        for (int e = 0; e < 8; ++e) {
            if (mk[e] != cur) {
                if (own) row[cur] = f2bf(s);
                cur = mk[e]; s = wk[e]; own = true;
            } else if (own) {
                s += wk[e];
            }
        }
        if (own) {
            int g = 8 * lane + 8;
            while (g < NNZ && mask[base + g] == cur) { s += w[base + g]; ++g; }
            row[cur] = f2bf(s);
        }

        uint4* out = (uint4*)(Wb + (size_t)rrow * IN_F);
#pragma unroll
        for (int j = 0; j < 8; ++j) out[lane + 64 * j] = rv[lane + 64 * j];
    } else {
        const int b1 = b - 1024;
        const float4* xv = (const float4*)x;
        uint4* xo = (uint4*)Xb;
#pragma unroll
        for (int it = 0; it < 4; ++it) {
            const int i = b1 * 256 + t + it * 524288;   // 2048 blk * 256 thr
            float4 a = xv[2 * i];
            float4 c = xv[2 * i + 1];
            uint4 o;
            o.x = (unsigned)f2bf(a.x) | ((unsigned)f2bf(a.y) << 16);
            o.y = (unsigned)f2bf(a.z) | ((unsigned)f2bf(a.w) << 16);
            o.z = (unsigned)f2bf(c.x) | ((unsigned)f2bf(c.y) << 16);
            o.w = (unsigned)f2bf(c.z) | ((unsigned)f2bf(c.w) << 16);
            xo[i] = o;
        }
    }
}

// ---------------------------------------------------------------------------
// R6 GEMM: 256x256 tile, 32x32x16 MFMA, restructured 4-phase -> 2-phase to fix
// R5's exposed MFMA dependency chains (R5: 2 acc chains/phase, dep distance
// 2 instr ~ 16cy ~= 32x32 MFMA latency -> pipe stall, MfmaUtil 38%).
// Now 16 MFMAs/phase over TWO quadrants = 4 chains, dep distance 4 instr.
// Also halves barrier count (4/tile vs 8/tile).
//
// Per tile t (buf b=t&1), 2 phases:
//  P1: ds A-X(8)+B-U(4)+B-V(4); stage A-Y(t+1)->b^1; lgkm(8); bar; lgkm(0);
//      16 MFMA Q00+Q01 interleaved; bar
//  P2: ds A-Y(8); stage A-X,B-U,B-V(t+2)->b; bar; lgkm(0);
//      16 MFMA Q11+Q10 interleaved; vmcnt(6); bar
// Race proof: every stage's target slots were read in a phase whose MFMA
// (behind lgkm(0)) completed before the barrier preceding the stage issue:
//  - AY(t+1)->b^1.Y: b^1.Y last read in t-1's P2, done before t-1's final bar.
//  - AX/BU/BV(t+2)->b.{X,U,V}: read in t's P1, done before P1's end bar;
//    stages issue after it. b.Y (being read in P2) is disjoint.
// vmcnt(6) at tile end leaves exactly the 3 t+2 half-tiles in flight =>
// tile t+1 (AX/BU/BV from t-1's P2 + AY from t's P1) fully landed; the final
// barrier makes it cross-wave visible before t+1's reads.
//
// Fragment layouts (32x32x16 bf16):
//   A/B input: row/col = lane&31, k = (lane>>5)*8 + j
//   C/D:       col = lane&31, row = (reg&3) + 8*(reg>>2) + 4*(lane>>5)
// Both verified by R5's passing absmax.
// ---------------------------------------------------------------------------

#define GLL16(src, dst) \
    __builtin_amdgcn_global_load_lds((__attribute__((address_space(1))) void*)(src), \
                                     (__attribute__((address_space(3))) void*)(dst), 16, 0, 0)

__global__ __launch_bounds__(512, 2) void gemm_bt_bias(
        const unsigned short* __restrict__ A,
        const unsigned short* __restrict__ B,
        const float* __restrict__ bias,
        float* __restrict__ C) {
    __shared__ unsigned short As[2][16384];
    __shared__ unsigned short Bs[2][16384];

    const int tid  = threadIdx.x;
    const int wave = tid >> 6;
    const int lane = tid & 63;
    const int rl   = lane & 31;      // fragment row/col
    const int hi   = lane >> 5;      // k-half select
    const int r7   = rl & 7;         // swizzle key (LDS row & 7)
    const int wm2  = wave >> 2;      // 0..1  (M group)
    const int wn4  = wave & 3;       // 0..3  (N group)

    // XCD-aware bijective swizzle: 256 blocks, 8 XCDs, 32 contiguous per XCD
    const int bid = blockIdx.x;
    const int swz = (bid & 7) * 32 + (bid >> 3);
    const int m0  = (swz >> 4) << 8;
    const int n0  = (swz & 15) << 8;

    // ---- staging source offsets (32-bit element offsets)
    const int r   = tid >> 3;                        // 0..63
    const int cse = ((tid & 7) ^ (r & 7)) * 8;       // swizzled source chunk
    const int oAX0 = (m0 + r)       * IN_F + cse;
    const int oAX1 = (m0 + 128 + r) * IN_F + cse;
    const int oAY0 = (m0 +  64 + r) * IN_F + cse;
    const int oAY1 = (m0 + 192 + r) * IN_F + cse;
    const int bc_  = (r >> 5) * 64 + (r & 31);
    const int oBU0 = (n0 + bc_)        * IN_F + cse;
    const int oBU1 = (n0 + 128 + bc_)  * IN_F + cse;
    const int oBV0 = (n0 +  32 + bc_)  * IN_F + cse;
    const int oBV1 = (n0 + 160 + bc_)  * IN_F + cse;
    const int wofs = wave * 512;                     // wave-uniform LDS dest

#define STAGE_AX(bb, kk) { GLL16(A + oAX0 + (kk), &As[bb][        wofs]); \
                           GLL16(A + oAX1 + (kk), &As[bb][ 4096 + wofs]); }
#define STAGE_AY(bb, kk) { GLL16(A + oAY0 + (kk), &As[bb][ 8192 + wofs]); \
                           GLL16(A + oAY1 + (kk), &As[bb][12288 + wofs]); }
#define STAGE_BU(bb, kk) { GLL16(B + oBU0 + (kk), &Bs[bb][        wofs]); \
                           GLL16(B + oBU1 + (kk), &Bs[bb][ 4096 + wofs]); }
#define STAGE_BV(bb, kk) { GLL16(B + oBV0 + (kk), &Bs[bb][ 8192 + wofs]); \
                           GLL16(B + oBV1 + (kk), &Bs[bb][12288 + wofs]); }

    // ---- ds_read row bases (ushort units); chunk slot(ks) = ((ks*2+hi)^r7)*8
    const int aX = (wm2 * 64 + rl) * 64;             // + mi*2048, mi in {0,1}
    const int aY = aX + 8192;
    const int bU = (wn4 * 32 + rl) * 64;
    const int bV = bU + 8192;

    floatx16 acc[4][2] = {};                          // 128 regs (unified file)
    bf16x8 af[2][4], bu[4], bv[4];

    // ---- prologue: tile0 complete (8 loads) + tile1 partial (6 loads)
    STAGE_AX(0, 0); STAGE_BU(0, 0); STAGE_BV(0, 0); STAGE_AY(0, 0);
    STAGE_AX(1, 64); STAGE_BU(1, 64); STAGE_BV(1, 64);
    asm volatile("s_waitcnt vmcnt(6)" ::: "memory");
    __builtin_amdgcn_s_barrier();

#define TILE_STEP(T, BB)                                                          \
    {                                                                             \
        const unsigned short* sA = As[BB];                                        \
        const unsigned short* sB = Bs[BB];                                        \
        const int kk1 = ((T) + 1 < 64 ? (T) + 1 : 63) * 64;                       \
        const int kk2 = ((T) + 2 < 64 ? (T) + 2 : 63) * 64;                       \
        /* ======== phase 1: Q00 + Q01 (A-X x B-U, A-X x B-V) ======== */         \
        _Pragma("unroll")                                                         \
        for (int mi = 0; mi < 2; ++mi)                                            \
            _Pragma("unroll")                                                     \
            for (int ks = 0; ks < 4; ++ks)                                        \
                af[mi][ks] = *(const bf16x8*)(sA + aX + mi * 2048 +               \
                                              (((ks * 2 + hi) ^ r7) * 8));        \
        _Pragma("unroll")                                                         \
        for (int ks = 0; ks < 4; ++ks)                                            \
            bu[ks] = *(const bf16x8*)(sB + bU + (((ks * 2 + hi) ^ r7) * 8));      \
        _Pragma("unroll")                                                         \
        for (int ks = 0; ks < 4; ++ks)                                            \
            bv[ks] = *(const bf16x8*)(sB + bV + (((ks * 2 + hi) ^ r7) * 8));      \
        STAGE_AY((BB) ^ 1, kk1);                                                  \
        asm volatile("s_waitcnt lgkmcnt(8)" ::: "memory");                        \
        __builtin_amdgcn_s_barrier();                                             \
        asm volatile("s_waitcnt lgkmcnt(0)" ::: "memory");                        \
        __builtin_amdgcn_s_setprio(1);                                            \
        _Pragma("unroll")                                                         \
        for (int ks = 0; ks < 4; ++ks) {                                          \
            _Pragma("unroll")                                                     \
            for (int mi = 0; mi < 2; ++mi)                                        \
                acc[mi][0] = __builtin_amdgcn_mfma_f32_32x32x16_bf16(             \
                    af[mi][ks], bu[ks], acc[mi][0], 0, 0, 0);                     \
            _Pragma("unroll")                                                     \
            for (int mi = 0; mi < 2; ++mi)                                        \
                acc[mi][1] = __builtin_amdgcn_mfma_f32_32x32x16_bf16(             \
                    af[mi][ks], bv[ks], acc[mi][1], 0, 0, 0);                     \
        }                                                                         \
        __builtin_amdgcn_s_setprio(0);                                            \
        __builtin_amdgcn_s_barrier();                                             \
        /* ======== phase 2: Q11 + Q10 (A-Y x B-V, A-Y x B-U) ======== */         \
        _Pragma("unroll")                                                         \
        for (int mi = 0; mi < 2; ++mi)                                            \
            _Pragma("unroll")                                                     \
            for (int ks = 0; ks < 4; ++ks)                                        \
                af[mi][ks] = *(const bf16x8*)(sA + aY + mi * 2048 +               \
                                              (((ks * 2 + hi) ^ r7) * 8));        \
        STAGE_AX((BB), kk2);                                                      \
        STAGE_BU((BB), kk2);                                                      \
        STAGE_BV((BB), kk2);                                                      \
        __builtin_amdgcn_s_barrier();                                             \
        asm volatile("s_waitcnt lgkmcnt(0)" ::: "memory");                        \
        __builtin_amdgcn_s_setprio(1);                                            \
        _Pragma("unroll")                                                         \
        for (int ks = 0; ks < 4; ++ks) {                                          \
            _Pragma("unroll")                                                     \
            for (int mi = 0; mi < 2; ++mi)                                        \
                acc[2 + mi][1] = __builtin_amdgcn_mfma_f32_32x32x16_bf16(         \
                    af[mi][ks], bv[ks], acc[2 + mi][1], 0, 0, 0);                 \
            _Pragma("unroll")                                                     \
            for (int mi = 0; mi < 2; ++mi)                                        \
                acc[2 + mi][0] = __builtin_amdgcn_mfma_f32_32x32x16_bf16(         \
                    af[mi][ks], bu[ks], acc[2 + mi][0], 0, 0, 0);                 \
        }                                                                         \
        __builtin_amdgcn_s_setprio(0);                                            \
        asm volatile("s_waitcnt vmcnt(6)" ::: "memory");                          \
        __builtin_amdgcn_s_barrier();                                             \
    }

    for (int tt = 0; tt < 32; ++tt) {
        TILE_STEP(2 * tt,     0);
        TILE_STEP(2 * tt + 1, 1);
    }

    // ---- epilogue: 32x32 C/D layout: col = lane&31,
    //      row = (reg&3) + 8*(reg>>2) + 4*(lane>>5)   [verified: R5 passed]
#pragma unroll
    for (int ni = 0; ni < 2; ++ni) {
        const int n = n0 + wn4 * 64 + ni * 32 + rl;
        const float bb = bias[n];
#pragma unroll
        for (int mi = 0; mi < 4; ++mi) {
            const int mbase = m0 + wm2 * 128 + mi * 32 + hi * 4;
#pragma unroll
            for (int rr = 0; rr < 16; ++rr) {
                const int m = mbase + (rr & 3) + 8 * (rr >> 2);
                C[(size_t)m * OUT_F + n] = acc[mi][ni][rr] + bb;
            }
        }
    }
}

extern "C" void kernel_launch(void* const* d_in, const int* in_sizes, int n_in,
                              void* d_out, int out_size, void* d_ws, size_t ws_size,
                              hipStream_t stream) {
    const float* x    = (const float*)d_in[0];   // [4096,4096] fp32
    const float* w    = (const float*)d_in[1];   // [4096,512]  fp32
    const int*   mask = (const int*)d_in[2];     // [4096,512]  int32 (sorted rows)
    const float* bias = (const float*)d_in[3];   // [4096]      fp32
    float* out = (float*)d_out;                  // [4096,4096] fp32

    unsigned short* Xb = (unsigned short*)d_ws;                 // 32 MiB
    unsigned short* Wb = Xb + (size_t)TOKENS * IN_F;            // 32 MiB

    prep_fused<<<3072, 256, 0, stream>>>(x, w, mask, Xb, Wb);
    gemm_bt_bias<<<dim3(256), dim3(512), 0, stream>>>(Xb, Wb, bias, out);
}

// Round 9
// 253.136 us; speedup vs baseline: 1.0523x; 1.0523x over previous
//
#include <hip/hip_runtime.h>
#include <hip/hip_bf16.h>
#include <stdint.h>

#define TOKENS 4096
#define IN_F   4096
#define OUT_F  4096
#define NNZ    512

using floatx4 = __attribute__((ext_vector_type(4))) float;
using bf16x8  = __attribute__((ext_vector_type(8))) __bf16;

__device__ __forceinline__ unsigned short f2bf(float v) {
    unsigned int u = __float_as_uint(v);
    u += 0x7FFFu + ((u >> 16) & 1u);   // RNE
    return (unsigned short)(u >> 16);
}

// ---------------------------------------------------------------------------
// Prep (R4 structure; residual shown invariant to prep structure):
//  blocks [0, 1024)    : W path. 4 waves/block, one row per wave, no barriers.
//  blocks [1024, 3072) : X path. fp32 -> bf16, 4 iters x 8 elems per thread.
// NOTE (R9): source is a semantically-null perturbation of R7/R8 (renamed
// macro, reordered independent decls, new comments) to dodge any artifact
// cache keyed on source hash after two identical-source container failures.
// ---------------------------------------------------------------------------
__global__ __launch_bounds__(256) void prep_fused(
        const float* __restrict__ x,
        const float* __restrict__ w,
        const int*   __restrict__ mask,
        unsigned short* __restrict__ Xb,
        unsigned short* __restrict__ Wb) {
    __shared__ unsigned short rows[4][IN_F];   // 32 KB
    const int t = threadIdx.x;
    const int b = blockIdx.x;

    if (b < 1024) {
        const int lane = t & 63;
        const int wave = t >> 6;
        const int rrow = b * 4 + wave;
        unsigned short* row = rows[wave];
        uint4* rv = (uint4*)row;
        const uint4 z = make_uint4(0u, 0u, 0u, 0u);
#pragma unroll
        for (int j = 0; j < 8; ++j) rv[lane + 64 * j] = z;   // full 512-uint4 row

        const int base = rrow * NNZ;
        const float4* w4 = (const float4*)(w + base);
        const int4*   m4 = (const int4*)(mask + base);
        const int4   ma = m4[2 * lane], mb2 = m4[2 * lane + 1];
        const float4 wa = w4[2 * lane], wb2 = w4[2 * lane + 1];
        const int   mk[8] = {ma.x, ma.y, ma.z, ma.w, mb2.x, mb2.y, mb2.z, mb2.w};
        const float wk[8] = {wa.x, wa.y, wa.z, wa.w, wb2.x, wb2.y, wb2.z, wb2.w};

        // run-leader scan: exactly one owner lane per run of equal indices.
        int   cur = (lane == 0) ? -1 : mask[base + 8 * lane - 1];
        float s   = 0.0f;
        bool  own = false;
#pragma unroll
        for (int e = 0; e < 8; ++e) {
            if (mk[e] != cur) {
                if (own) row[cur] = f2bf(s);
                cur = mk[e]; s = wk[e]; own = true;
            } else if (own) {
                s += wk[e];
            }
        }
        if (own) {
            int g = 8 * lane + 8;
            while (g < NNZ && mask[base + g] == cur) { s += w[base + g]; ++g; }
            row[cur] = f2bf(s);
        }

        uint4* out = (uint4*)(Wb + (size_t)rrow * IN_F);
#pragma unroll
        for (int j = 0; j < 8; ++j) out[lane + 64 * j] = rv[lane + 64 * j];
    } else {
        const int b1 = b - 1024;
        const float4* xv = (const float4*)x;
        uint4* xo = (uint4*)Xb;
#pragma unroll
        for (int it = 0; it < 4; ++it) {
            const int i = b1 * 256 + t + it * 524288;   // 2048 blocks x 256 thr
            float4 a = xv[2 * i];
            float4 c = xv[2 * i + 1];
            uint4 o;
            o.x = (unsigned)f2bf(a.x) | ((unsigned)f2bf(a.y) << 16);
            o.y = (unsigned)f2bf(a.z) | ((unsigned)f2bf(a.w) << 16);
            o.z = (unsigned)f2bf(c.x) | ((unsigned)f2bf(c.y) << 16);
            o.w = (unsigned)f2bf(c.z) | ((unsigned)f2bf(c.w) << 16);
            xo[i] = o;
        }
    }
}

// ---------------------------------------------------------------------------
// R9 GEMM (same machine code intent as R7/R8): R2 16x16x32 structure
// (best measured 131.3us, conflicts 0, plain C stores) with ks-OUTER MFMA
// ordering — dependent MFMAs on one accumulator are 8 instructions apart
// instead of adjacent. Numerics identical (each acc gets ks=0 then ks=1).
//
// Per tile t (buf b=t&1), 4 phases, 2 raw s_barrier each, counted vmcnt only:
//   P1: ds A-X(8)+B-U(4); stage A-Y(t+1)->b^1; lgkm(8); bar; lgkm(0); 16 MFMA Q00
//   P2: ds B-V(4);        stage A-X(t+2)->b  ;           bar; lgkm(0); 16 MFMA Q01
//   P3: ds A-Y(8);        stage B-U(t+2)->b  ;           bar; lgkm(0); 16 MFMA Q11
//   P4: (reg reuse);      stage B-V(t+2)->b  ;           bar; 16 MFMA Q10; vmcnt(6)
// Race proof: X/U read only in P1, V in P2, Y in P3 -> every stage target was
// freed by the previous phase's end barrier. vmcnt(6) at tile end leaves
// exactly the 3 t+2 half-tiles in flight => tile t+1 fully landed per-wave;
// the following s_barrier makes it cross-wave visible before t+1's reads.
// ---------------------------------------------------------------------------

#define G2L16(src, dst) \
    __builtin_amdgcn_global_load_lds((__attribute__((address_space(1))) void*)(src), \
                                     (__attribute__((address_space(3))) void*)(dst), 16, 0, 0)

__global__ __launch_bounds__(512, 2) void gemm_bt_bias(
        const unsigned short* __restrict__ A,
        const unsigned short* __restrict__ B,
        const float* __restrict__ bias,
        float* __restrict__ C) {
    __shared__ unsigned short As[2][16384];
    __shared__ unsigned short Bs[2][16384];

    const int tid  = threadIdx.x;
    const int lane = tid & 63;
    const int wave = tid >> 6;
    const int lm   = lane & 15;
    const int lq   = lane >> 4;
    const int lm7  = lm & 7;
    const int wn4  = wave & 3;      // 0..3  (N group)
    const int wm2  = wave >> 2;     // 0..1  (M group)

    // XCD-aware bijective swizzle: 256 blocks, 8 XCDs, 32 contiguous per XCD
    const int bid = blockIdx.x;
    const int swz = (bid & 7) * 32 + (bid >> 3);
    const int n0  = (swz & 15) << 8;
    const int m0  = (swz >> 4) << 8;

    // ---- staging source offsets (32-bit element offsets)
    const int r   = tid >> 3;                        // 0..63
    const int cse = ((tid & 7) ^ (r & 7)) * 8;       // swizzled source chunk
    const int bc_  = (r >> 5) * 64 + (r & 31);
    const int oAX0 = (m0 + r)       * IN_F + cse;
    const int oAX1 = (m0 + 128 + r) * IN_F + cse;
    const int oAY0 = (m0 +  64 + r) * IN_F + cse;
    const int oAY1 = (m0 + 192 + r) * IN_F + cse;
    const int oBU0 = (n0 + bc_)        * IN_F + cse;
    const int oBU1 = (n0 + 128 + bc_)  * IN_F + cse;
    const int oBV0 = (n0 +  32 + bc_)  * IN_F + cse;
    const int oBV1 = (n0 + 160 + bc_)  * IN_F + cse;
    const int wofs = wave * 512;                     // wave-uniform LDS dest

#define STAGE_AX(bb, kk) { G2L16(A + oAX0 + (kk), &As[bb][        wofs]); \
                           G2L16(A + oAX1 + (kk), &As[bb][ 4096 + wofs]); }
#define STAGE_AY(bb, kk) { G2L16(A + oAY0 + (kk), &As[bb][ 8192 + wofs]); \
                           G2L16(A + oAY1 + (kk), &As[bb][12288 + wofs]); }
#define STAGE_BU(bb, kk) { G2L16(B + oBU0 + (kk), &Bs[bb][        wofs]); \
                           G2L16(B + oBU1 + (kk), &Bs[bb][ 4096 + wofs]); }
#define STAGE_BV(bb, kk) { G2L16(B + oBV0 + (kk), &Bs[bb][ 8192 + wofs]); \
                           G2L16(B + oBV1 + (kk), &Bs[bb][12288 + wofs]); }

    // ---- ds_read offsets (ushort units)
    const int ck0 = (lq ^ lm7) * 8;
    const int ck1 = ck0 ^ 32;
    const int aX  = (wm2 * 64 + lm) * 64;
    const int aY  = aX + 8192;
    const int bU  = (wn4 * 32 + lm) * 64;
    const int bV  = bU + 8192;

    floatx4 acc[8][4] = {};
    bf16x8 af[4][2], bu[2][2], bv[2][2];

    // ---- prologue: tile0 complete (8 loads) + tile1 partial (6 loads)
    STAGE_AX(0, 0); STAGE_BU(0, 0); STAGE_BV(0, 0); STAGE_AY(0, 0);
    STAGE_AX(1, 64); STAGE_BU(1, 64); STAGE_BV(1, 64);
    asm volatile("s_waitcnt vmcnt(6)" ::: "memory");
    __builtin_amdgcn_s_barrier();

#define TILE_STEP(T, BB)                                                          \
    {                                                                             \
        const unsigned short* sA = As[BB];                                        \
        const unsigned short* sB = Bs[BB];                                        \
        const int kk1 = ((T) + 1 < 64 ? (T) + 1 : 63) * 64;                       \
        const int kk2 = ((T) + 2 < 64 ? (T) + 2 : 63) * 64;                       \
        /* ---- phase 1: Q00 ---- */                                              \
        _Pragma("unroll")                                                         \
        for (int mi = 0; mi < 4; ++mi) {                                          \
            af[mi][0] = *(const bf16x8*)(sA + aX + mi * 1024 + ck0);              \
            af[mi][1] = *(const bf16x8*)(sA + aX + mi * 1024 + ck1);              \
        }                                                                         \
        _Pragma("unroll")                                                         \
        for (int ni = 0; ni < 2; ++ni) {                                          \
            bu[ni][0] = *(const bf16x8*)(sB + bU + ni * 1024 + ck0);              \
            bu[ni][1] = *(const bf16x8*)(sB + bU + ni * 1024 + ck1);              \
        }                                                                         \
        STAGE_AY((BB) ^ 1, kk1);                                                  \
        asm volatile("s_waitcnt lgkmcnt(8)" ::: "memory");                        \
        __builtin_amdgcn_s_barrier();                                             \
        asm volatile("s_waitcnt lgkmcnt(0)" ::: "memory");                        \
        __builtin_amdgcn_s_setprio(1);                                            \
        _Pragma("unroll")                                                         \
        for (int ks = 0; ks < 2; ++ks)                                            \
            _Pragma("unroll")                                                     \
            for (int mi = 0; mi < 4; ++mi)                                        \
                _Pragma("unroll")                                                 \
                for (int ni = 0; ni < 2; ++ni)                                    \
                    acc[mi][ni] = __builtin_amdgcn_mfma_f32_16x16x32_bf16(        \
                        af[mi][ks], bu[ni][ks], acc[mi][ni], 0, 0, 0);            \
        __builtin_amdgcn_s_setprio(0);                                            \
        __builtin_amdgcn_s_barrier();                                             \
        /* ---- phase 2: Q01 ---- */                                              \
        _Pragma("unroll")                                                         \
        for (int ni = 0; ni < 2; ++ni) {                                          \
            bv[ni][0] = *(const bf16x8*)(sB + bV + ni * 1024 + ck0);              \
            bv[ni][1] = *(const bf16x8*)(sB + bV + ni * 1024 + ck1);              \
        }                                                                         \
        STAGE_AX((BB), kk2);                                                      \
        __builtin_amdgcn_s_barrier();                                             \
        asm volatile("s_waitcnt lgkmcnt(0)" ::: "memory");                        \
        __builtin_amdgcn_s_setprio(1);                                            \
        _Pragma("unroll")                                                         \
        for (int ks = 0; ks < 2; ++ks)                                            \
            _Pragma("unroll")                                                     \
            for (int mi = 0; mi < 4; ++mi)                                        \
                _Pragma("unroll")                                                 \
                for (int ni = 0; ni < 2; ++ni)                                    \
                    acc[mi][2 + ni] = __builtin_amdgcn_mfma_f32_16x16x32_bf16(    \
                        af[mi][ks], bv[ni][ks], acc[mi][2 + ni], 0, 0, 0);        \
        __builtin_amdgcn_s_setprio(0);                                            \
        __builtin_amdgcn_s_barrier();                                             \
        /* ---- phase 3: Q11 ---- */                                              \
        _Pragma("unroll")                                                         \
        for (int mi = 0; mi < 4; ++mi) {                                          \
            af[mi][0] = *(const bf16x8*)(sA + aY + mi * 1024 + ck0);              \
            af[mi][1] = *(const bf16x8*)(sA + aY + mi * 1024 + ck1);              \
        }                                                                         \
        STAGE_BU((BB), kk2);                                                      \
        __builtin_amdgcn_s_barrier();                                             \
        asm volatile("s_waitcnt lgkmcnt(0)" ::: "memory");                        \
        __builtin_amdgcn_s_setprio(1);                                            \
        _Pragma("unroll")                                                         \
        for (int ks = 0; ks < 2; ++ks)                                            \
            _Pragma("unroll")                                                     \
            for (int mi = 0; mi < 4; ++mi)                                        \
                _Pragma("unroll")                                                 \
                for (int ni = 0; ni < 2; ++ni)                                    \
                    acc[4 + mi][2 + ni] = __builtin_amdgcn_mfma_f32_16x16x32_bf16(\
                        af[mi][ks], bv[ni][ks], acc[4 + mi][2 + ni], 0, 0, 0);    \
        __builtin_amdgcn_s_setprio(0);                                            \
        __builtin_amdgcn_s_barrier();                                             \
        /* ---- phase 4: Q10 (pure register reuse) ---- */                        \
        STAGE_BV((BB), kk2);                                                      \
        __builtin_amdgcn_s_barrier();                                             \
        __builtin_amdgcn_s_setprio(1);                                            \
        _Pragma("unroll")                                                         \
        for (int ks = 0; ks < 2; ++ks)                                            \
            _Pragma("unroll")                                                     \
            for (int mi = 0; mi < 4; ++mi)                                        \
                _Pragma("unroll")                                                 \
                for (int ni = 0; ni < 2; ++ni)                                    \
                    acc[4 + mi][ni] = __builtin_amdgcn_mfma_f32_16x16x32_bf16(    \
                        af[mi][ks], bu[ni][ks], acc[4 + mi][ni], 0, 0, 0);        \
        __builtin_amdgcn_s_setprio(0);                                            \
        asm volatile("s_waitcnt vmcnt(6)" ::: "memory");                          \
        __builtin_amdgcn_s_barrier();                                             \
    }

    for (int tt = 0; tt < 32; ++tt) {
        TILE_STEP(2 * tt,     0);
        TILE_STEP(2 * tt + 1, 1);
    }

    // ---- epilogue: C/D layout col = lane&15, row = (lane>>4)*4 + reg  [m89]
#pragma unroll
    for (int ni = 0; ni < 4; ++ni) {
        const int n = n0 + wn4 * 64 + ni * 16 + lm;
        const float bb = bias[n];
#pragma unroll
        for (int mi = 0; mi < 8; ++mi) {
            const int mb = m0 + wm2 * 128 + mi * 16 + lq * 4;
#pragma unroll
            for (int rr = 0; rr < 4; ++rr) {
                C[(size_t)(mb + rr) * OUT_F + n] = acc[mi][ni][rr] + bb;
            }
        }
    }
}

extern "C" void kernel_launch(void* const* d_in, const int* in_sizes, int n_in,
                              void* d_out, int out_size, void* d_ws, size_t ws_size,
                              hipStream_t stream) {
    const float* x    = (const float*)d_in[0];   // [4096,4096] fp32
    const float* w    = (const float*)d_in[1];   // [4096,512]  fp32
    const int*   mask = (const int*)d_in[2];     // [4096,512]  int32 (sorted rows)
    const float* bias = (const float*)d_in[3];   // [4096]      fp32
    float* out = (float*)d_out;                  // [4096,4096] fp32

    unsigned short* Xb = (unsigned short*)d_ws;                 // 32 MiB
    unsigned short* Wb = Xb + (size_t)TOKENS * IN_F;            // 32 MiB

    prep_fused<<<3072, 256, 0, stream>>>(x, w, mask, Xb, Wb);
    gemm_bt_bias<<<dim3(256), dim3(512), 0, stream>>>(Xb, Wb, bias, out);
}